// Round 3
// baseline (57.772 us; speedup 1.0000x reference)
//
#include <hip/hip_runtime.h>
#include <math.h>

#define D 100
#define K 4
#define NREL 1000
#define CH 8
#define NT 512
#define MAXB 64   // max batch items per relation; B=4096 over 1000 rels -> Poisson(4.1), max ~15

// One block per relation. The block discovers its own batch items (rels scan,
// L2-hot), stages e1/e2 in LDS, streams W[r] ONCE (per <=8-item chunk) with
// wave (k, half-of-rows) ownership and unroll-5 MLP, reduces, applies epilogue.
__global__ __launch_bounds__(NT) void ntn_fused(
    const int* __restrict__ heads, const int* __restrict__ tails,
    const int* __restrict__ rels,
    const float* __restrict__ E, const float* __restrict__ W,
    const float* __restrict__ V, const float* __restrict__ Bp,
    const float* __restrict__ U, float* __restrict__ out, int B)
{
    const int r    = blockIdx.x;
    const int tid  = threadIdx.x;
    const int lane = tid & 63;
    const int w    = tid >> 6;      // wave 0..7
    const int k    = w & 3;         // tensor slice
    const int half = w >> 2;        // row half: [half*50, half*50+50)
    const int dsub = lane / 25;     // 0/1 for lanes < 50
    const int c    = lane % 25;     // float4 column group
    const bool active = (lane < 50);

    __shared__ int   bb[MAXB];
    __shared__ int   cntS;
    __shared__ float e12[CH][2 * D];
    __shared__ float red[8][CH];

    if (tid == 0) cntS = 0;
    __syncthreads();
    // Find this relation's batch items (order-independent per-item work).
    for (int b = tid; b < B; b += NT) {
        if (rels[b] == r) {
            int p = atomicAdd(&cntS, 1);
            if (p < MAXB) bb[p] = b;
        }
    }
    __syncthreads();
    const int n = min(cntS, MAXB);
    if (n == 0) return;

    const float* Wk = W + ((size_t)r * K + k) * D * D;   // this wave's slice
    const float* Vr = V + (size_t)r * K * 2 * D;

    for (int base = 0; base < n; base += CH) {
        const int m = min(CH, n - base);
        __syncthreads();  // previous chunk fully consumed before overwriting e12
        for (int idx = tid; idx < CH * 2 * D; idx += NT) {
            const int it = idx / (2 * D), j = idx % (2 * D);
            float val = 0.f;
            if (it < m) {
                const int b = bb[base + it];
                const int ent = (j < D) ? heads[b] : tails[b];
                val = E[(size_t)ent * D + (j < D ? j : j - D)];
            }
            e12[it][j] = val;
        }
        __syncthreads();

        // e2 column-group per item -> registers (loaded once per chunk)
        float4 e2r[CH];
        #pragma unroll
        for (int it = 0; it < CH; ++it)
            e2r[it] = active ? *(const float4*)&e12[it][D + c * 4]
                             : make_float4(0.f, 0.f, 0.f, 0.f);

        float acc[CH];
        #pragma unroll
        for (int it = 0; it < CH; ++it) acc[it] = 0.f;

        if (active) {
            #pragma unroll 5   // 5 independent W float4 loads in flight
            for (int dp = 0; dp < 25; ++dp) {
                const int d = half * 50 + dp * 2 + dsub;
                const float4 wv = *(const float4*)&Wk[d * D + c * 4];
                #pragma unroll
                for (int it = 0; it < CH; ++it) {
                    acc[it] += (wv.x * e2r[it].x + wv.y * e2r[it].y
                              + wv.z * e2r[it].z + wv.w * e2r[it].w) * e12[it][d];
                }
            }
        }
        // g_a: only one row-half contributes v . [e1;e2]
        if (half == 0) {
            for (int j = lane; j < 2 * D; j += 64) {
                const float vv = Vr[k * 2 * D + j];
                #pragma unroll
                for (int it = 0; it < CH; ++it) acc[it] += vv * e12[it][j];
            }
        }
        #pragma unroll
        for (int it = 0; it < CH; ++it) {
            float s = acc[it];
            #pragma unroll
            for (int off = 32; off > 0; off >>= 1) s += __shfl_down(s, off, 64);
            if (lane == 0) red[w][it] = s;
        }
        __syncthreads();
        if (tid < m) {
            float score = 0.f;
            #pragma unroll
            for (int kk = 0; kk < K; ++kk) {
                const float g = red[kk][tid] + red[4 + kk][tid] + Bp[r * K + kk];
                score += U[r * K + kk] * tanhf(g);
            }
            out[bb[base + tid]] = 1.f / (1.f + expf(-score));
        }
    }
}

extern "C" void kernel_launch(void* const* d_in, const int* in_sizes, int n_in,
                              void* d_out, int out_size, void* d_ws, size_t ws_size,
                              hipStream_t stream) {
    const int*   heads = (const int*)d_in[0];
    const int*   tails = (const int*)d_in[1];
    const int*   rels  = (const int*)d_in[2];
    const float* E     = (const float*)d_in[3];
    const float* W     = (const float*)d_in[4];
    const float* V     = (const float*)d_in[5];
    const float* Bp    = (const float*)d_in[6];
    const float* U     = (const float*)d_in[7];
    float* out = (float*)d_out;

    const int B = in_sizes[0];
    ntn_fused<<<NREL, NT, 0, stream>>>(heads, tails, rels, E, W, V, Bp, U, out, B);
}